// Round 1
// baseline (8595.021 us; speedup 1.0000x reference)
//
#include <hip/hip_runtime.h>
#include <cstddef>

// ---------------------------------------------------------------------------
// RQ-VAE forward on MI355X. Round 1: all-fp32 direct kernels, correctness-first.
// Encoder + RVQ must stay fp32 (argmin indices graded ~exactly).
// ---------------------------------------------------------------------------

template<int ACT> __device__ __forceinline__ float actf(float v) {
    if constexpr (ACT == 1) return v > 0.f ? v : 0.f;          // relu
    else if constexpr (ACT == 2) return v > 0.f ? v : 0.01f * v; // leaky relu 0.01
    else return v;
}

__device__ __forceinline__ float lrelu_in(float v) { return v > 0.f ? v : 0.01f * v; }

// ---------------------------------------------------------------------------
// Generic direct conv: thread = 1 output pixel x 16 output channels.
// Weights staged in LDS (float4 broadcast reads); inputs via global/L1.
// ---------------------------------------------------------------------------
template<int CIN, int COUT, int K, int S, int P, int HIN, int WIN, int HOUT, int WOUT,
         int ICC, int ACT, bool BIAS>
__launch_bounds__(256)
__global__ void conv_k(const float* __restrict__ in, const float* __restrict__ w,
                       const float* __restrict__ bias, float* __restrict__ out)
{
    constexpr int K2 = K * K;
    __shared__ float sw[ICC * K2 * 16];
    const int tid = threadIdx.x;
    const int tx = tid & 15, ty = tid >> 4;
    constexpr int TW = WOUT / 16;
    const int bx = blockIdx.x % TW, by = blockIdx.x / TW;
    const int ox = bx * 16 + tx, oy = by * 16 + ty;
    const int oc0 = blockIdx.y * 16;
    const int n = blockIdx.z;
    const int ix0 = ox * S - P, iy0 = oy * S - P;

    float acc[16];
#pragma unroll
    for (int j = 0; j < 16; ++j) acc[j] = 0.f;

    for (int ic0 = 0; ic0 < CIN; ic0 += ICC) {
        __syncthreads();
        for (int t = tid; t < ICC * K2 * 16; t += 256) {
            int oc_l = t & 15, r = t >> 4, k = r % K2, ic_l = r / K2;
            sw[(ic_l * K2 + k) * 16 + oc_l] =
                w[((size_t)(oc0 + oc_l) * CIN + ic0 + ic_l) * K2 + k];
        }
        __syncthreads();
#pragma unroll 2
        for (int ic_l = 0; ic_l < ICC; ++ic_l) {
            const float* ip = in + (size_t)(n * CIN + ic0 + ic_l) * HIN * WIN;
            const float* swp = &sw[ic_l * K2 * 16];
#pragma unroll
            for (int ky = 0; ky < K; ++ky) {
                const int iy = iy0 + ky;
#pragma unroll
                for (int kx = 0; kx < K; ++kx) {
                    const int ix = ix0 + kx;
                    float v = 0.f;
                    if (iy >= 0 && iy < HIN && ix >= 0 && ix < WIN) v = ip[iy * WIN + ix];
                    const float4* wp = (const float4*)&swp[(ky * K + kx) * 16];
#pragma unroll
                    for (int q4 = 0; q4 < 4; ++q4) {
                        float4 wv = wp[q4];
                        acc[q4 * 4 + 0] = fmaf(wv.x, v, acc[q4 * 4 + 0]);
                        acc[q4 * 4 + 1] = fmaf(wv.y, v, acc[q4 * 4 + 1]);
                        acc[q4 * 4 + 2] = fmaf(wv.z, v, acc[q4 * 4 + 2]);
                        acc[q4 * 4 + 3] = fmaf(wv.w, v, acc[q4 * 4 + 3]);
                    }
                }
            }
        }
    }
#pragma unroll
    for (int j = 0; j < 16; ++j) {
        float r = acc[j];
        if (BIAS) r += bias[oc0 + j];
        r = actf<ACT>(r);
        out[((size_t)(n * COUT + oc0 + j) * HOUT + oy) * WOUT + ox] = r;
    }
}

// ---------------------------------------------------------------------------
// 1x1 conv over 64x64 maps (HW=4096). Optional: input-lrelu (fused preceding
// activation), bias, out-activation, residual add, token-major output (for z).
// ---------------------------------------------------------------------------
template<int CIN, int COUT, int ACT, bool BIAS, bool INL, bool RESID, bool TOK>
__launch_bounds__(256)
__global__ void conv1x1_k(const float* __restrict__ in, const float* __restrict__ w,
                          const float* __restrict__ bias, const float* __restrict__ resid,
                          float* __restrict__ out)
{
    constexpr int HW = 4096;
    __shared__ float sw[16 * CIN];
    const int tid = threadIdx.x;
    const int pix = blockIdx.x * 256 + tid;
    const int oc0 = blockIdx.y * 16;
    const int n = blockIdx.z;

    for (int t = tid; t < 16 * CIN; t += 256) {
        int oc_l = t & 15, ic = t >> 4;
        sw[ic * 16 + oc_l] = w[(size_t)(oc0 + oc_l) * CIN + ic];
    }
    __syncthreads();

    float acc[16];
#pragma unroll
    for (int j = 0; j < 16; ++j) acc[j] = 0.f;

    const float* ip = in + (size_t)n * CIN * HW + pix;
#pragma unroll 4
    for (int ic = 0; ic < CIN; ++ic) {
        float v = ip[(size_t)ic * HW];
        if (INL) v = lrelu_in(v);
        const float4* wp = (const float4*)&sw[ic * 16];
#pragma unroll
        for (int q4 = 0; q4 < 4; ++q4) {
            float4 wv = wp[q4];
            acc[q4 * 4 + 0] = fmaf(wv.x, v, acc[q4 * 4 + 0]);
            acc[q4 * 4 + 1] = fmaf(wv.y, v, acc[q4 * 4 + 1]);
            acc[q4 * 4 + 2] = fmaf(wv.z, v, acc[q4 * 4 + 2]);
            acc[q4 * 4 + 3] = fmaf(wv.w, v, acc[q4 * 4 + 3]);
        }
    }
#pragma unroll
    for (int j = 0; j < 16; ++j) {
        float r = acc[j];
        if (BIAS) r += bias[oc0 + j];
        r = actf<ACT>(r);
        if (RESID) r += resid[((size_t)(n * COUT + oc0 + j)) * HW + pix];
        if (TOK)
            out[((size_t)n * HW + pix) * COUT + oc0 + j] = r;
        else
            out[((size_t)(n * COUT + oc0 + j)) * HW + pix] = r;
    }
}

// ---------------------------------------------------------------------------
// ConvTranspose2d k=4 s=2 p=1 via parity decomposition: thread = 2x2 output
// pixels x OCT channels. Each (ky,kx) tap maps to exactly one of the 4 outputs.
// ---------------------------------------------------------------------------
template<int CIN, int COUT, int OCT, int HIN, int ICC, int ACT, bool INL>
__launch_bounds__(256)
__global__ void convt_k(const float* __restrict__ in, const float* __restrict__ w,
                        const float* __restrict__ bias, float* __restrict__ out)
{
    constexpr int WIN = HIN, HOUT = 2 * HIN, WOUT = 2 * HIN;
    __shared__ float sw[ICC * 16 * OCT];
    const int tid = threadIdx.x;
    const int tx = tid & 15, ty = tid >> 4;
    constexpr int TBW = WOUT / 32;
    const int bx = blockIdx.x % TBW, by = blockIdx.x / TBW;
    const int A = by * 16 + ty;   // outputs rows 2A, 2A+1
    const int C = bx * 16 + tx;   // outputs cols 2C, 2C+1
    const int oc0 = blockIdx.y * OCT;
    const int n = blockIdx.z;

    float acc[4 * OCT];
#pragma unroll
    for (int j = 0; j < 4 * OCT; ++j) acc[j] = 0.f;

    for (int ic0 = 0; ic0 < CIN; ic0 += ICC) {
        __syncthreads();
        for (int t = tid; t < ICC * 16 * OCT; t += 256) {
            int oc_l = t % OCT, r = t / OCT, k = r & 15, ic_l = r >> 4;
            sw[(ic_l * 16 + k) * OCT + oc_l] =
                w[((size_t)(ic0 + ic_l) * COUT + oc0 + oc_l) * 16 + k];
        }
        __syncthreads();
#pragma unroll 1
        for (int ic_l = 0; ic_l < ICC; ++ic_l) {
            const float* ip = in + (size_t)(n * CIN + ic0 + ic_l) * HIN * WIN;
            float in9[3][3];
#pragma unroll
            for (int dy = 0; dy < 3; ++dy) {
                const int iy = A - 1 + dy;
#pragma unroll
                for (int dx = 0; dx < 3; ++dx) {
                    const int ix = C - 1 + dx;
                    float v = 0.f;
                    if (iy >= 0 && iy < HIN && ix >= 0 && ix < WIN) v = ip[iy * WIN + ix];
                    if (INL) v = lrelu_in(v);
                    in9[dy][dx] = v;
                }
            }
#pragma unroll
            for (int ky = 0; ky < 4; ++ky) {
                const int ry = (ky + 1) & 1;
                const int dy = 2 - ((ky + 1) >> 1);   // {2,1,1,0}
#pragma unroll
                for (int kx = 0; kx < 4; ++kx) {
                    const int rx = (kx + 1) & 1;
                    const int dx = 2 - ((kx + 1) >> 1);
                    const float v = in9[dy][dx];
                    const int po = ry * 2 + rx;
                    const float4* wp = (const float4*)&sw[(ic_l * 16 + ky * 4 + kx) * OCT];
#pragma unroll
                    for (int q4 = 0; q4 < OCT / 4; ++q4) {
                        float4 wv = wp[q4];
                        acc[po * OCT + q4 * 4 + 0] = fmaf(wv.x, v, acc[po * OCT + q4 * 4 + 0]);
                        acc[po * OCT + q4 * 4 + 1] = fmaf(wv.y, v, acc[po * OCT + q4 * 4 + 1]);
                        acc[po * OCT + q4 * 4 + 2] = fmaf(wv.z, v, acc[po * OCT + q4 * 4 + 2]);
                        acc[po * OCT + q4 * 4 + 3] = fmaf(wv.w, v, acc[po * OCT + q4 * 4 + 3]);
                    }
                }
            }
        }
    }
#pragma unroll
    for (int po = 0; po < 4; ++po) {
        const int ry = po >> 1, rx = po & 1;
        const int oy = 2 * A + ry, ox = 2 * C + rx;
#pragma unroll
        for (int j = 0; j < OCT; ++j) {
            float r = acc[po * OCT + j] + bias[oc0 + j];
            r = actf<ACT>(r);
            out[((size_t)(n * COUT + oc0 + j) * HOUT + oy) * WOUT + ox] = r;
        }
    }
}

// ---------------------------------------------------------------------------
// Residual VQ: thread = 1 token (r[64] in regs). 4 stages x (4 passes of 128
// codes staged in 32KB LDS). d = |r|^2 - 2 r.cb + |cb|^2 (same form as ref),
// strict < keeps first min (matches jnp.argmin ties).
// ---------------------------------------------------------------------------
__launch_bounds__(256)
__global__ void rvq_k(const float* __restrict__ z, const float* __restrict__ cb,
                      float* __restrict__ q, float* __restrict__ idx_out,
                      float* __restrict__ loss_acc)
{
    __shared__ float scb[128 * 64];
    __shared__ float ssc[128];
    const int tid = threadIdx.x;
    const int t = blockIdx.x * 256 + tid;

    float r[64], qs[64];
    const float4* zp = (const float4*)(z + (size_t)t * 64);
#pragma unroll
    for (int i = 0; i < 16; ++i) {
        float4 v = zp[i];
        r[4 * i + 0] = v.x; r[4 * i + 1] = v.y; r[4 * i + 2] = v.z; r[4 * i + 3] = v.w;
    }
#pragma unroll
    for (int i = 0; i < 64; ++i) qs[i] = 0.f;

    for (int s = 0; s < 4; ++s) {
        float s0 = 0.f, s1 = 0.f, s2 = 0.f, s3 = 0.f;
#pragma unroll
        for (int i = 0; i < 64; i += 4) {
            s0 = fmaf(r[i + 0], r[i + 0], s0);
            s1 = fmaf(r[i + 1], r[i + 1], s1);
            s2 = fmaf(r[i + 2], r[i + 2], s2);
            s3 = fmaf(r[i + 3], r[i + 3], s3);
        }
        const float sr2 = (s0 + s1) + (s2 + s3);

        float dmin = 3.4e38f;
        int best = 0;
        for (int pass = 0; pass < 4; ++pass) {
            __syncthreads();
            const float* src = cb + ((size_t)s * 512 + pass * 128) * 64;
            for (int i2 = tid; i2 < 128 * 64 / 4; i2 += 256)
                ((float4*)scb)[i2] = ((const float4*)src)[i2];
            if (tid < 128) {
                const float* cc = src + (size_t)tid * 64;
                float a = 0.f;
#pragma unroll
                for (int i = 0; i < 64; ++i) a = fmaf(cc[i], cc[i], a);
                ssc[tid] = a;
            }
            __syncthreads();
#pragma unroll 2
            for (int kk = 0; kk < 128; ++kk) {
                const float4* cp = (const float4*)&scb[kk * 64];
                float d0 = 0.f, d1 = 0.f, d2 = 0.f, d3 = 0.f;
#pragma unroll
                for (int i = 0; i < 16; ++i) {
                    float4 c = cp[i];
                    d0 = fmaf(r[4 * i + 0], c.x, d0);
                    d1 = fmaf(r[4 * i + 1], c.y, d1);
                    d2 = fmaf(r[4 * i + 2], c.z, d2);
                    d3 = fmaf(r[4 * i + 3], c.w, d3);
                }
                const float dot = (d0 + d1) + (d2 + d3);
                const float d = fmaf(-2.f, dot, sr2) + ssc[kk];
                if (d < dmin) { dmin = d; best = pass * 128 + kk; }
            }
        }
        // loss partial: sum of dmin over tokens
        float lv = dmin;
#pragma unroll
        for (int off = 32; off; off >>= 1) lv += __shfl_down(lv, off, 64);
        if ((tid & 63) == 0) atomicAdd(&loss_acc[s], lv);

        idx_out[(size_t)t * 4 + s] = (float)best;

        const float* cbest = cb + ((size_t)s * 512 + best) * 64;
#pragma unroll
        for (int i = 0; i < 64; ++i) {
            float c = cbest[i];
            qs[i] += c;
            r[i] -= c;
        }
    }
    // write q_out back in NCHW (n,64,64,64)
    const int n = t >> 12, pix = t & 4095;
    float* qp = q + (size_t)n * 64 * 4096 + pix;
#pragma unroll
    for (int i = 0; i < 64; ++i) qp[(size_t)i * 4096] = qs[i];
}

__global__ void init_k(float* loss_acc) {
    if (threadIdx.x < 4) loss_acc[threadIdx.x] = 0.f;
}

__global__ void fin_k(const float* __restrict__ loss_acc, float* __restrict__ out_loss) {
    if (threadIdx.x < 4)
        out_loss[threadIdx.x] = loss_acc[threadIdx.x] * (0.25f / 4194304.f); // BETA/(N*D)
}

// ---------------------------------------------------------------------------
extern "C" void kernel_launch(void* const* d_in, const int* in_sizes, int n_in,
                              void* d_out, int out_size, void* d_ws, size_t ws_size,
                              hipStream_t stream)
{
    const float* x    = (const float*)d_in[0];
    const float* e1w  = (const float*)d_in[1];  const float* e1b = (const float*)d_in[2];
    const float* e2w  = (const float*)d_in[3];  const float* e2b = (const float*)d_in[4];
    const float* e3w  = (const float*)d_in[5];  const float* e3b = (const float*)d_in[6];
    const float* r1aw = (const float*)d_in[7];  const float* r1bw = (const float*)d_in[8];
    const float* r2aw = (const float*)d_in[9];  const float* r2bw = (const float*)d_in[10];
    const float* e4w  = (const float*)d_in[11]; const float* e4b = (const float*)d_in[12];
    const float* cbs  = (const float*)d_in[13];
    const float* d1w  = (const float*)d_in[14]; const float* d1b = (const float*)d_in[15];
    const float* dr1aw= (const float*)d_in[16]; const float* dr1bw = (const float*)d_in[17];
    const float* dr2aw= (const float*)d_in[18]; const float* dr2bw = (const float*)d_in[19];
    const float* dt1w = (const float*)d_in[20]; const float* dt1b = (const float*)d_in[21];
    const float* dt2w = (const float*)d_in[22]; const float* dt2b = (const float*)d_in[23];

    float* out = (float*)d_out;
    float* ws  = (float*)d_ws;

    // ws layout (floats): BIG 16.78M (halves P2,P3) | P1 8.39M | Z 4.19M | Q 4.19M | LACC
    float* BIG = ws;
    float* P2  = BIG;
    float* P3  = BIG + 8388608;
    float* P1  = ws + 16777216;
    float* Z   = ws + 25165824;
    float* Q   = ws + 29360128;
    float* LACC= ws + 33554432;

    float* out_recons = out;                    // 16*4*256*256 = 4194304
    float* out_idx    = out + 4194304;          // 16*64*64*4   = 262144
    float* out_loss   = out + 4194304 + 262144; // 4

    init_k<<<1, 64, 0, stream>>>(LACC);

    // ---- encoder ----
    conv_k<4, 64, 4, 2, 1, 256, 256, 128, 128, 4, 2, true>
        <<<dim3(64, 4, 16), 256, 0, stream>>>(x, e1w, e1b, BIG);
    conv_k<64, 128, 4, 2, 1, 128, 128, 64, 64, 16, 2, true>
        <<<dim3(16, 8, 16), 256, 0, stream>>>(BIG, e2w, e2b, P1);
    conv_k<128, 128, 3, 1, 1, 64, 64, 64, 64, 16, 2, true>
        <<<dim3(16, 8, 16), 256, 0, stream>>>(P1, e3w, e3b, P2);
    conv_k<128, 128, 3, 1, 1, 64, 64, 64, 64, 16, 1, false>
        <<<dim3(16, 8, 16), 256, 0, stream>>>(P2, r1aw, nullptr, P3);
    conv1x1_k<128, 128, 0, false, false, true, false>
        <<<dim3(16, 8, 16), 256, 0, stream>>>(P3, r1bw, nullptr, P2, P1);
    conv_k<128, 128, 3, 1, 1, 64, 64, 64, 64, 16, 1, false>
        <<<dim3(16, 8, 16), 256, 0, stream>>>(P1, r2aw, nullptr, P3);
    conv1x1_k<128, 128, 0, false, false, true, false>
        <<<dim3(16, 8, 16), 256, 0, stream>>>(P3, r2bw, nullptr, P1, P2);
    // e4: lrelu on input (post-res activation), bias, lrelu out, token-major z
    conv1x1_k<128, 64, 2, true, true, false, true>
        <<<dim3(16, 4, 16), 256, 0, stream>>>(P2, e4w, e4b, nullptr, Z);

    // ---- residual VQ ----
    rvq_k<<<256, 256, 0, stream>>>(Z, cbs, Q, out_idx, LACC);
    fin_k<<<1, 64, 0, stream>>>(LACC, out_loss);

    // ---- decoder ----
    conv_k<64, 128, 3, 1, 1, 64, 64, 64, 64, 16, 2, true>
        <<<dim3(16, 8, 16), 256, 0, stream>>>(Q, d1w, d1b, P1);
    conv_k<128, 128, 3, 1, 1, 64, 64, 64, 64, 16, 1, false>
        <<<dim3(16, 8, 16), 256, 0, stream>>>(P1, dr1aw, nullptr, P2);
    conv1x1_k<128, 128, 0, false, false, true, false>
        <<<dim3(16, 8, 16), 256, 0, stream>>>(P2, dr1bw, nullptr, P1, P3);
    conv_k<128, 128, 3, 1, 1, 64, 64, 64, 64, 16, 1, false>
        <<<dim3(16, 8, 16), 256, 0, stream>>>(P3, dr2aw, nullptr, P2);
    conv1x1_k<128, 128, 0, false, false, true, false>
        <<<dim3(16, 8, 16), 256, 0, stream>>>(P2, dr2bw, nullptr, P3, P1);
    // dt1: lrelu fused on input load
    convt_k<128, 64, 16, 64, 8, 2, true>
        <<<dim3(16, 4, 16), 256, 0, stream>>>(P1, dt1w, dt1b, BIG);
    convt_k<64, 4, 4, 128, 16, 1, false>
        <<<dim3(64, 1, 16), 256, 0, stream>>>(BIG, dt2w, dt2b, out_recons);
}

// Round 2
// 4600.219 us; speedup vs baseline: 1.8684x; 1.8684x over previous
//
#include <hip/hip_runtime.h>
#include <cstddef>

// ---------------------------------------------------------------------------
// RQ-VAE forward on MI355X. Round 2: despill the direct convs.
// R1 post-mortem: conv kernels hit VGPR=256 + scratch spills (4.6 GB HBM
// writes on e2 alone). Fix: unroll 1 on ic loop, precomputed tap offsets and
// masks, launch_bounds to cap VGPRs.
// ---------------------------------------------------------------------------

template<int ACT> __device__ __forceinline__ float actf(float v) {
    if constexpr (ACT == 1) return v > 0.f ? v : 0.f;            // relu
    else if constexpr (ACT == 2) return v > 0.f ? v : 0.01f * v; // leaky relu
    else return v;
}

__device__ __forceinline__ float lrelu_in(float v) { return v > 0.f ? v : 0.01f * v; }

// ---------------------------------------------------------------------------
// Direct conv: thread = 1 output pixel x 16 output channels.
// Weights in LDS (float4 broadcast); inputs via L1/L2 with precomputed
// offsets+masks (ic-invariant). unroll 1 over ic keeps ~<=128 VGPR live.
// ---------------------------------------------------------------------------
template<int CIN, int COUT, int K, int S, int P, int HIN, int WIN, int HOUT, int WOUT,
         int ICC, int ACT, bool BIAS>
__launch_bounds__(256, 4)
__global__ void conv_k(const float* __restrict__ in, const float* __restrict__ w,
                       const float* __restrict__ bias, float* __restrict__ out)
{
    constexpr int K2 = K * K;
    __shared__ float sw[ICC * K2 * 16];
    const int tid = threadIdx.x;
    const int tx = tid & 15, ty = tid >> 4;
    constexpr int TW = WOUT / 16;
    const int bx = blockIdx.x % TW, by = blockIdx.x / TW;
    const int ox = bx * 16 + tx, oy = by * 16 + ty;
    const int oc0 = blockIdx.y * 16;
    const int n = blockIdx.z;
    const int ix0 = ox * S - P, iy0 = oy * S - P;

    // ic-invariant tap offsets + masks
    int offs[K2];
    float msk[K2];
#pragma unroll
    for (int ky = 0; ky < K; ++ky) {
#pragma unroll
        for (int kx = 0; kx < K; ++kx) {
            const int iy = iy0 + ky, ix = ix0 + kx;
            const bool v = (iy >= 0) && (iy < HIN) && (ix >= 0) && (ix < WIN);
            offs[ky * K + kx] = v ? iy * WIN + ix : 0;
            msk[ky * K + kx] = v ? 1.f : 0.f;
        }
    }

    float acc[16];
#pragma unroll
    for (int j = 0; j < 16; ++j) acc[j] = 0.f;

    for (int ic0 = 0; ic0 < CIN; ic0 += ICC) {
        __syncthreads();
        for (int t = tid; t < ICC * K2 * 16; t += 256) {
            int oc_l = t & 15, r = t >> 4, k = r % K2, ic_l = r / K2;
            sw[(ic_l * K2 + k) * 16 + oc_l] =
                w[((size_t)(oc0 + oc_l) * CIN + ic0 + ic_l) * K2 + k];
        }
        __syncthreads();
#pragma unroll 1
        for (int ic_l = 0; ic_l < ICC; ++ic_l) {
            const float* ip = in + (size_t)(n * CIN + ic0 + ic_l) * HIN * WIN;
            const float* swp = &sw[ic_l * K2 * 16];
#pragma unroll
            for (int k = 0; k < K2; ++k) {
                const float v = ip[offs[k]] * msk[k];
                const float4* wp = (const float4*)&swp[k * 16];
#pragma unroll
                for (int q4 = 0; q4 < 4; ++q4) {
                    float4 wv = wp[q4];
                    acc[q4 * 4 + 0] = fmaf(wv.x, v, acc[q4 * 4 + 0]);
                    acc[q4 * 4 + 1] = fmaf(wv.y, v, acc[q4 * 4 + 1]);
                    acc[q4 * 4 + 2] = fmaf(wv.z, v, acc[q4 * 4 + 2]);
                    acc[q4 * 4 + 3] = fmaf(wv.w, v, acc[q4 * 4 + 3]);
                }
            }
        }
    }
#pragma unroll
    for (int j = 0; j < 16; ++j) {
        float r = acc[j];
        if (BIAS) r += bias[oc0 + j];
        r = actf<ACT>(r);
        out[((size_t)(n * COUT + oc0 + j) * HOUT + oy) * WOUT + ox] = r;
    }
}

// ---------------------------------------------------------------------------
// 1x1 conv over 64x64 maps (HW=4096).
// ---------------------------------------------------------------------------
template<int CIN, int COUT, int ACT, bool BIAS, bool INL, bool RESID, bool TOK>
__launch_bounds__(256, 4)
__global__ void conv1x1_k(const float* __restrict__ in, const float* __restrict__ w,
                          const float* __restrict__ bias, const float* __restrict__ resid,
                          float* __restrict__ out)
{
    constexpr int HW = 4096;
    __shared__ float sw[16 * CIN];
    const int tid = threadIdx.x;
    const int pix = blockIdx.x * 256 + tid;
    const int oc0 = blockIdx.y * 16;
    const int n = blockIdx.z;

    for (int t = tid; t < 16 * CIN; t += 256) {
        int oc_l = t & 15, ic = t >> 4;
        sw[ic * 16 + oc_l] = w[(size_t)(oc0 + oc_l) * CIN + ic];
    }
    __syncthreads();

    float acc[16];
#pragma unroll
    for (int j = 0; j < 16; ++j) acc[j] = 0.f;

    const float* ip = in + (size_t)n * CIN * HW + pix;
#pragma unroll 4
    for (int ic = 0; ic < CIN; ++ic) {
        float v = ip[(size_t)ic * HW];
        if (INL) v = lrelu_in(v);
        const float4* wp = (const float4*)&sw[ic * 16];
#pragma unroll
        for (int q4 = 0; q4 < 4; ++q4) {
            float4 wv = wp[q4];
            acc[q4 * 4 + 0] = fmaf(wv.x, v, acc[q4 * 4 + 0]);
            acc[q4 * 4 + 1] = fmaf(wv.y, v, acc[q4 * 4 + 1]);
            acc[q4 * 4 + 2] = fmaf(wv.z, v, acc[q4 * 4 + 2]);
            acc[q4 * 4 + 3] = fmaf(wv.w, v, acc[q4 * 4 + 3]);
        }
    }
#pragma unroll
    for (int j = 0; j < 16; ++j) {
        float r = acc[j];
        if (BIAS) r += bias[oc0 + j];
        r = actf<ACT>(r);
        if (RESID) r += resid[((size_t)(n * COUT + oc0 + j)) * HW + pix];
        if (TOK)
            out[((size_t)n * HW + pix) * COUT + oc0 + j] = r;
        else
            out[((size_t)(n * COUT + oc0 + j)) * HW + pix] = r;
    }
}

// ---------------------------------------------------------------------------
// ConvTranspose2d k=4 s=2 p=1, parity decomposition: thread = 2x2 out pixels
// x OCT channels. Precomputed 3x3 input offsets/masks; unroll 1 over ic.
// ---------------------------------------------------------------------------
template<int CIN, int COUT, int OCT, int HIN, int ICC, int ACT, bool INL>
__launch_bounds__(256, 3)
__global__ void convt_k(const float* __restrict__ in, const float* __restrict__ w,
                        const float* __restrict__ bias, float* __restrict__ out)
{
    constexpr int WIN = HIN, HOUT = 2 * HIN, WOUT = 2 * HIN;
    __shared__ float sw[ICC * 16 * OCT];
    const int tid = threadIdx.x;
    const int tx = tid & 15, ty = tid >> 4;
    constexpr int TBW = WOUT / 32;
    const int bx = blockIdx.x % TBW, by = blockIdx.x / TBW;
    const int A = by * 16 + ty;   // output rows 2A, 2A+1
    const int C = bx * 16 + tx;   // output cols 2C, 2C+1
    const int oc0 = blockIdx.y * OCT;
    const int n = blockIdx.z;

    int offs[9];
    float msk[9];
#pragma unroll
    for (int dy = 0; dy < 3; ++dy) {
#pragma unroll
        for (int dx = 0; dx < 3; ++dx) {
            const int iy = A - 1 + dy, ix = C - 1 + dx;
            const bool v = (iy >= 0) && (iy < HIN) && (ix >= 0) && (ix < WIN);
            offs[dy * 3 + dx] = v ? iy * WIN + ix : 0;
            msk[dy * 3 + dx] = v ? 1.f : 0.f;
        }
    }

    float acc[4 * OCT];
#pragma unroll
    for (int j = 0; j < 4 * OCT; ++j) acc[j] = 0.f;

    for (int ic0 = 0; ic0 < CIN; ic0 += ICC) {
        __syncthreads();
        for (int t = tid; t < ICC * 16 * OCT; t += 256) {
            int oc_l = t % OCT, r = t / OCT, k = r & 15, ic_l = r >> 4;
            sw[(ic_l * 16 + k) * OCT + oc_l] =
                w[((size_t)(ic0 + ic_l) * COUT + oc0 + oc_l) * 16 + k];
        }
        __syncthreads();
#pragma unroll 1
        for (int ic_l = 0; ic_l < ICC; ++ic_l) {
            const float* ip = in + (size_t)(n * CIN + ic0 + ic_l) * HIN * WIN;
            float in9[9];
#pragma unroll
            for (int j = 0; j < 9; ++j) {
                float v = ip[offs[j]] * msk[j];
                if (INL) v = lrelu_in(v);
                in9[j] = v;
            }
#pragma unroll
            for (int ky = 0; ky < 4; ++ky) {
                const int ry = (ky + 1) & 1;
                const int dy = 2 - ((ky + 1) >> 1);   // {2,1,1,0}
#pragma unroll
                for (int kx = 0; kx < 4; ++kx) {
                    const int rx = (kx + 1) & 1;
                    const int dx = 2 - ((kx + 1) >> 1);
                    const float v = in9[dy * 3 + dx];
                    const int po = ry * 2 + rx;
                    const float4* wp = (const float4*)&sw[(ic_l * 16 + ky * 4 + kx) * OCT];
#pragma unroll
                    for (int q4 = 0; q4 < OCT / 4; ++q4) {
                        float4 wv = wp[q4];
                        acc[po * OCT + q4 * 4 + 0] = fmaf(wv.x, v, acc[po * OCT + q4 * 4 + 0]);
                        acc[po * OCT + q4 * 4 + 1] = fmaf(wv.y, v, acc[po * OCT + q4 * 4 + 1]);
                        acc[po * OCT + q4 * 4 + 2] = fmaf(wv.z, v, acc[po * OCT + q4 * 4 + 2]);
                        acc[po * OCT + q4 * 4 + 3] = fmaf(wv.w, v, acc[po * OCT + q4 * 4 + 3]);
                    }
                }
            }
        }
    }
#pragma unroll
    for (int po = 0; po < 4; ++po) {
        const int ry = po >> 1, rx = po & 1;
        const int oy = 2 * A + ry, ox = 2 * C + rx;
#pragma unroll
        for (int j = 0; j < OCT; ++j) {
            float r = acc[po * OCT + j] + bias[oc0 + j];
            r = actf<ACT>(r);
            out[((size_t)(n * COUT + oc0 + j) * HOUT + oy) * WOUT + ox] = r;
        }
    }
}

// ---------------------------------------------------------------------------
// Residual VQ: thread = 1 token (r[64] in regs). 4 stages x (4 passes of 128
// codes in LDS). Strict < keeps first min (matches jnp.argmin ties).
// ---------------------------------------------------------------------------
__launch_bounds__(256)
__global__ void rvq_k(const float* __restrict__ z, const float* __restrict__ cb,
                      float* __restrict__ q, float* __restrict__ idx_out,
                      float* __restrict__ loss_acc)
{
    __shared__ float scb[128 * 64];
    __shared__ float ssc[128];
    const int tid = threadIdx.x;
    const int t = blockIdx.x * 256 + tid;

    float r[64], qs[64];
    const float4* zp = (const float4*)(z + (size_t)t * 64);
#pragma unroll
    for (int i = 0; i < 16; ++i) {
        float4 v = zp[i];
        r[4 * i + 0] = v.x; r[4 * i + 1] = v.y; r[4 * i + 2] = v.z; r[4 * i + 3] = v.w;
    }
#pragma unroll
    for (int i = 0; i < 64; ++i) qs[i] = 0.f;

    for (int s = 0; s < 4; ++s) {
        float s0 = 0.f, s1 = 0.f, s2 = 0.f, s3 = 0.f;
#pragma unroll
        for (int i = 0; i < 64; i += 4) {
            s0 = fmaf(r[i + 0], r[i + 0], s0);
            s1 = fmaf(r[i + 1], r[i + 1], s1);
            s2 = fmaf(r[i + 2], r[i + 2], s2);
            s3 = fmaf(r[i + 3], r[i + 3], s3);
        }
        const float sr2 = (s0 + s1) + (s2 + s3);

        float dmin = 3.4e38f;
        int best = 0;
        for (int pass = 0; pass < 4; ++pass) {
            __syncthreads();
            const float* src = cb + ((size_t)s * 512 + pass * 128) * 64;
            for (int i2 = tid; i2 < 128 * 64 / 4; i2 += 256)
                ((float4*)scb)[i2] = ((const float4*)src)[i2];
            if (tid < 128) {
                const float* cc = src + (size_t)tid * 64;
                float a = 0.f;
#pragma unroll
                for (int i = 0; i < 64; ++i) a = fmaf(cc[i], cc[i], a);
                ssc[tid] = a;
            }
            __syncthreads();
#pragma unroll 2
            for (int kk = 0; kk < 128; ++kk) {
                const float4* cp = (const float4*)&scb[kk * 64];
                float d0 = 0.f, d1 = 0.f, d2 = 0.f, d3 = 0.f;
#pragma unroll
                for (int i = 0; i < 16; ++i) {
                    float4 c = cp[i];
                    d0 = fmaf(r[4 * i + 0], c.x, d0);
                    d1 = fmaf(r[4 * i + 1], c.y, d1);
                    d2 = fmaf(r[4 * i + 2], c.z, d2);
                    d3 = fmaf(r[4 * i + 3], c.w, d3);
                }
                const float dot = (d0 + d1) + (d2 + d3);
                const float d = fmaf(-2.f, dot, sr2) + ssc[kk];
                if (d < dmin) { dmin = d; best = pass * 128 + kk; }
            }
        }
        float lv = dmin;
#pragma unroll
        for (int off = 32; off; off >>= 1) lv += __shfl_down(lv, off, 64);
        if ((tid & 63) == 0) atomicAdd(&loss_acc[s], lv);

        idx_out[(size_t)t * 4 + s] = (float)best;

        const float* cbest = cb + ((size_t)s * 512 + best) * 64;
#pragma unroll
        for (int i = 0; i < 64; ++i) {
            float c = cbest[i];
            qs[i] += c;
            r[i] -= c;
        }
    }
    const int n = t >> 12, pix = t & 4095;
    float* qp = q + (size_t)n * 64 * 4096 + pix;
#pragma unroll
    for (int i = 0; i < 64; ++i) qp[(size_t)i * 4096] = qs[i];
}

__global__ void init_k(float* loss_acc) {
    if (threadIdx.x < 4) loss_acc[threadIdx.x] = 0.f;
}

__global__ void fin_k(const float* __restrict__ loss_acc, float* __restrict__ out_loss) {
    if (threadIdx.x < 4)
        out_loss[threadIdx.x] = loss_acc[threadIdx.x] * (0.25f / 4194304.f); // BETA/(N*D)
}

// ---------------------------------------------------------------------------
extern "C" void kernel_launch(void* const* d_in, const int* in_sizes, int n_in,
                              void* d_out, int out_size, void* d_ws, size_t ws_size,
                              hipStream_t stream)
{
    const float* x    = (const float*)d_in[0];
    const float* e1w  = (const float*)d_in[1];  const float* e1b = (const float*)d_in[2];
    const float* e2w  = (const float*)d_in[3];  const float* e2b = (const float*)d_in[4];
    const float* e3w  = (const float*)d_in[5];  const float* e3b = (const float*)d_in[6];
    const float* r1aw = (const float*)d_in[7];  const float* r1bw = (const float*)d_in[8];
    const float* r2aw = (const float*)d_in[9];  const float* r2bw = (const float*)d_in[10];
    const float* e4w  = (const float*)d_in[11]; const float* e4b = (const float*)d_in[12];
    const float* cbs  = (const float*)d_in[13];
    const float* d1w  = (const float*)d_in[14]; const float* d1b = (const float*)d_in[15];
    const float* dr1aw= (const float*)d_in[16]; const float* dr1bw = (const float*)d_in[17];
    const float* dr2aw= (const float*)d_in[18]; const float* dr2bw = (const float*)d_in[19];
    const float* dt1w = (const float*)d_in[20]; const float* dt1b = (const float*)d_in[21];
    const float* dt2w = (const float*)d_in[22]; const float* dt2b = (const float*)d_in[23];

    float* out = (float*)d_out;
    float* ws  = (float*)d_ws;

    float* BIG = ws;
    float* P2  = BIG;
    float* P3  = BIG + 8388608;
    float* P1  = ws + 16777216;
    float* Z   = ws + 25165824;
    float* Q   = ws + 29360128;
    float* LACC= ws + 33554432;

    float* out_recons = out;                    // 16*4*256*256 = 4194304
    float* out_idx    = out + 4194304;          // 16*64*64*4   = 262144
    float* out_loss   = out + 4194304 + 262144; // 4

    init_k<<<1, 64, 0, stream>>>(LACC);

    // ---- encoder ----
    conv_k<4, 64, 4, 2, 1, 256, 256, 128, 128, 4, 2, true>
        <<<dim3(64, 4, 16), 256, 0, stream>>>(x, e1w, e1b, BIG);
    conv_k<64, 128, 4, 2, 1, 128, 128, 64, 64, 16, 2, true>
        <<<dim3(16, 8, 16), 256, 0, stream>>>(BIG, e2w, e2b, P1);
    conv_k<128, 128, 3, 1, 1, 64, 64, 64, 64, 16, 2, true>
        <<<dim3(16, 8, 16), 256, 0, stream>>>(P1, e3w, e3b, P2);
    conv_k<128, 128, 3, 1, 1, 64, 64, 64, 64, 16, 1, false>
        <<<dim3(16, 8, 16), 256, 0, stream>>>(P2, r1aw, nullptr, P3);
    conv1x1_k<128, 128, 0, false, false, true, false>
        <<<dim3(16, 8, 16), 256, 0, stream>>>(P3, r1bw, nullptr, P2, P1);
    conv_k<128, 128, 3, 1, 1, 64, 64, 64, 64, 16, 1, false>
        <<<dim3(16, 8, 16), 256, 0, stream>>>(P1, r2aw, nullptr, P3);
    conv1x1_k<128, 128, 0, false, false, true, false>
        <<<dim3(16, 8, 16), 256, 0, stream>>>(P3, r2bw, nullptr, P1, P2);
    conv1x1_k<128, 64, 2, true, true, false, true>
        <<<dim3(16, 4, 16), 256, 0, stream>>>(P2, e4w, e4b, nullptr, Z);

    // ---- residual VQ ----
    rvq_k<<<256, 256, 0, stream>>>(Z, cbs, Q, out_idx, LACC);
    fin_k<<<1, 64, 0, stream>>>(LACC, out_loss);

    // ---- decoder ----
    conv_k<64, 128, 3, 1, 1, 64, 64, 64, 64, 16, 2, true>
        <<<dim3(16, 8, 16), 256, 0, stream>>>(Q, d1w, d1b, P1);
    conv_k<128, 128, 3, 1, 1, 64, 64, 64, 64, 16, 1, false>
        <<<dim3(16, 8, 16), 256, 0, stream>>>(P1, dr1aw, nullptr, P2);
    conv1x1_k<128, 128, 0, false, false, true, false>
        <<<dim3(16, 8, 16), 256, 0, stream>>>(P2, dr1bw, nullptr, P1, P3);
    conv_k<128, 128, 3, 1, 1, 64, 64, 64, 64, 16, 1, false>
        <<<dim3(16, 8, 16), 256, 0, stream>>>(P3, dr2aw, nullptr, P2);
    conv1x1_k<128, 128, 0, false, false, true, false>
        <<<dim3(16, 8, 16), 256, 0, stream>>>(P2, dr2bw, nullptr, P3, P1);
    convt_k<128, 64, 16, 64, 8, 2, true>
        <<<dim3(16, 4, 16), 256, 0, stream>>>(P1, dt1w, dt1b, BIG);
    convt_k<64, 4, 4, 128, 16, 1, false>
        <<<dim3(64, 1, 16), 256, 0, stream>>>(BIG, dt2w, dt2b, out_recons);
}